// Round 5
// baseline (1261.978 us; speedup 1.0000x reference)
//
#include <hip/hip_runtime.h>
#include <math.h>

typedef __attribute__((ext_vector_type(8))) __bf16 bf16x8;
typedef __attribute__((ext_vector_type(4))) __bf16 bf16x4;
typedef __attribute__((ext_vector_type(2))) __bf16 bf16x2;
typedef __attribute__((ext_vector_type(4))) float f32x4;

#define MFMA16(a, b, c) __builtin_amdgcn_mfma_f32_16x16x32_bf16(a, b, c, 0, 0, 0)

typedef const __attribute__((address_space(1))) unsigned int* gas_t;
typedef __attribute__((address_space(3))) unsigned int* las_t;

__device__ __forceinline__ void g2lds16(const __bf16* g, __bf16* l) {
    __builtin_amdgcn_global_load_lds((gas_t)(const void*)g, (las_t)(void*)l, 16, 0, 0);
}

// ---------------------------------------------------------------- pack fp32->bf16
__global__ void pack_bf16(const float* __restrict__ src, __bf16* __restrict__ dst, int n4) {
    int idx = blockIdx.x * 256 + threadIdx.x;
    if (idx < n4) {
        float4 f = *(const float4*)(src + (size_t)idx * 4);
        bf16x4 o;
        o.x = (__bf16)f.x; o.y = (__bf16)f.y; o.z = (__bf16)f.z; o.w = (__bf16)f.w;
        *(bf16x4*)(dst + (size_t)idx * 4) = o;
    }
}

// ---------------------------------------------------------------- 256x256 8-phase GEMM, reg-prefetch pipelined
// C = A·B^T + bias. A: MxK bf16 rm. B: NxK bf16 rm. M,N % 256 == 0, K % 128 == 0.
// 8 waves (2M x 4N), BK=64, double-buffered LDS (128 KiB, 1 block/CU).
// Each phase: {R: ds_read prefetch for NEXT quadrant into alternate reg set; S: one
// global_load_lds half-tile stage; L: counted lgkmcnt draining only THIS quadrant's
// operands; BAR; MFMA cluster (new reads in flight underneath); VMW(8); BAR}.
// Hazard table (audited r3, re-audited r4):
//  - every stage of half X is >=2 barriers after the lgkm-drain of X's previous reads;
//  - VMW(8)/10-in-flight: each staged half completes exactly 1 phase before its ds_read,
//    each wait targets loads issued 4 phases (~2400cy) earlier -> latency fully hidden;
//  - counted lgkm: READ_AH=8 ds ops, READ_BH=4; waits leave exactly the new reads in flight;
//  - all barriers wave-uniform (no hang path).
// Register sets: aA/aB for A-halves; bA/bB ping-pong for B-halves per tile parity.

#define STAGE_A(bufi, hh, tt) do {                                                     \
    _Pragma("unroll")                                                                  \
    for (int l = 0; l < 2; ++l) {                                                      \
        int c = (l << 9) + tid, rh = c >> 3;                                           \
        int esw = ((c & 7) << 3) ^ ((rh & 7) << 3);                                    \
        int gm = m0 + ((rh >> 6) << 7) + ((hh) << 6) + (rh & 63);                      \
        g2lds16(A + (size_t)gm * K + ((tt) << 6) + esw, &As[bufi][hh][c << 3]);        \
    } } while (0)

#define STAGE_B(bufi, hh, tt) do {                                                     \
    _Pragma("unroll")                                                                  \
    for (int l = 0; l < 2; ++l) {                                                      \
        int c = (l << 9) + tid, rh = c >> 3;                                           \
        int esw = ((c & 7) << 3) ^ ((rh & 7) << 3);                                    \
        int gn = n0 + ((rh >> 5) << 6) + ((hh) << 5) + (rh & 31);                      \
        g2lds16(B + (size_t)gn * K + ((tt) << 6) + esw, &Bs[bufi][hh][c << 3]);        \
    } } while (0)

// 8 ds_read_b128 into dst[4][2]: A-half hh of buffer bufi
#define READ_AH(dst, bufi, hh) do {                                                    \
    _Pragma("unroll")                                                                  \
    for (int m2 = 0; m2 < 4; ++m2) {                                                   \
        _Pragma("unroll")                                                              \
        for (int kk = 0; kk < 2; ++kk)                                                 \
            dst[m2][kk] = *(const bf16x8*)&As[bufi][hh][                               \
                (((wm << 6) + (m2 << 4) + lm) << 6) + (((kk << 5) + q8) ^ swz)];       \
    } } while (0)

// 4 ds_read_b128 into dst[2][2]: B-half hh of buffer bufi
#define READ_BH(dst, bufi, hh) do {                                                    \
    _Pragma("unroll")                                                                  \
    for (int n2 = 0; n2 < 2; ++n2) {                                                   \
        _Pragma("unroll")                                                              \
        for (int kk = 0; kk < 2; ++kk)                                                 \
            dst[n2][kk] = *(const bf16x8*)&Bs[bufi][hh][                               \
                (((wn << 5) + (n2 << 4) + lm) << 6) + (((kk << 5) + q8) ^ swz)];       \
    } } while (0)

#define MMA_Q(Aset, mh, Bset, nh) do {                                                 \
    __builtin_amdgcn_s_setprio(1);                                                     \
    _Pragma("unroll")                                                                  \
    for (int m2 = 0; m2 < 4; ++m2) {                                                   \
        _Pragma("unroll")                                                              \
        for (int n2 = 0; n2 < 2; ++n2) {                                               \
            _Pragma("unroll")                                                          \
            for (int kk = 0; kk < 2; ++kk)                                             \
                acc[(mh) * 4 + m2][(nh) * 2 + n2] =                                    \
                    MFMA16(Aset[m2][kk], Bset[n2][kk], acc[(mh) * 4 + m2][(nh) * 2 + n2]); \
    } }                                                                                \
    __builtin_amdgcn_s_setprio(0); } while (0)

#define BAR __builtin_amdgcn_s_barrier()
#define SCHEDB __builtin_amdgcn_sched_barrier(0)
#define LGKM(n) asm volatile("s_waitcnt lgkmcnt(" #n ")" ::: "memory")
#define VMW(n) asm volatile("s_waitcnt vmcnt(" #n ")" ::: "memory")

template <typename OutT>
__global__ __launch_bounds__(512, 2)
void gemm256_bt_bias(const __bf16* __restrict__ A, const __bf16* __restrict__ B,
                     const float* __restrict__ bias, OutT* __restrict__ C,
                     int M, int N, int K) {
    __shared__ __align__(16) __bf16 As[2][2][8192];
    __shared__ __align__(16) __bf16 Bs[2][2][8192];

    const int tid = threadIdx.x;
    const int lane = tid & 63, wave = tid >> 6;
    const int lm = lane & 15, quad = lane >> 4, q8 = quad << 3;
    const int wm = wave >> 2, wn = wave & 3;
    const int swz = (lm & 7) << 3;

    // T1: XCD-aware bijective swizzle (grid sizes are % 8 == 0)
    const int nwg = gridDim.x;
    const int wg = (blockIdx.x & 7) * (nwg >> 3) + (blockIdx.x >> 3);
    const int nbx = N >> 8;
    const int m0 = (wg / nbx) << 8;
    const int n0 = (wg % nbx) << 8;

    const int NT = K >> 6, ITER = NT >> 1;

    f32x4 acc[8][4] = {};
    bf16x8 aA[4][2], aB[4][2], bA[2][2], bB[2][2];

    // prologue: buf0 A0,B0,B1 (must complete) then buf0 A1, buf1 A0,B0,B1 (stay in flight).
    STAGE_A(0, 0, 0); STAGE_B(0, 0, 0); STAGE_B(0, 1, 0);
    STAGE_A(0, 1, 0); STAGE_A(1, 0, 1); STAGE_B(1, 0, 1); STAGE_B(1, 1, 1);
    VMW(8);   // drains first 3 stages (6 loads); leaves 4 stages (8 loads) in flight
    BAR;
    READ_AH(aA, 0, 0); READ_BH(bA, 0, 0);   // 12 ds ops in flight (steady-state entry)

#pragma unroll 1
    for (int i = 0; i < ITER - 1; ++i) {
        const int b = 2 * i + 1, t2 = 2 * i + 2, t3 = 2 * i + 3;
        // ---- even tile (buf0): B0@bA, B1@bB
        READ_BH(bB, 0, 1); STAGE_A(1, 1, b);  LGKM(4); BAR; SCHEDB;
        MMA_Q(aA, 0, bA, 0); SCHEDB; VMW(8); BAR;
        READ_AH(aB, 0, 1); STAGE_A(0, 0, t2); LGKM(8); BAR; SCHEDB;
        MMA_Q(aA, 0, bB, 1); SCHEDB; VMW(8); BAR;
        READ_AH(aA, 1, 0); STAGE_B(0, 0, t2); LGKM(8); BAR; SCHEDB;
        MMA_Q(aB, 1, bB, 1); SCHEDB; VMW(8); BAR;
        READ_BH(bB, 1, 0); STAGE_B(0, 1, t2);          BAR; SCHEDB;
        MMA_Q(aB, 1, bA, 0); SCHEDB; VMW(8); BAR;
        // ---- odd tile (buf1): B0@bB, B1@bA
        READ_BH(bA, 1, 1); STAGE_A(0, 1, t2); LGKM(4); BAR; SCHEDB;
        MMA_Q(aA, 0, bB, 0); SCHEDB; VMW(8); BAR;
        READ_AH(aB, 1, 1); STAGE_A(1, 0, t3); LGKM(8); BAR; SCHEDB;
        MMA_Q(aA, 0, bA, 1); SCHEDB; VMW(8); BAR;
        READ_AH(aA, 0, 0); STAGE_B(1, 0, t3); LGKM(8); BAR; SCHEDB;
        MMA_Q(aB, 1, bA, 1); SCHEDB; VMW(8); BAR;
        READ_BH(bA, 0, 0); STAGE_B(1, 1, t3);          BAR; SCHEDB;
        MMA_Q(aB, 1, bB, 0); SCHEDB; VMW(8); BAR;
    }

    // ---- drain: tile NT-2 (buf0) then NT-1 (buf1); in-flight at entry:
    // vm: A(0,1,NT-2), A(1,0,NT-1), B(1,0,NT-1), B(1,1,NT-1);  ds: aA(8)+bA(4).
    {
        const int b = NT - 1;
        // even tile (buf0, NT-2)
        READ_BH(bB, 0, 1); STAGE_A(1, 1, b); LGKM(4); BAR; SCHEDB;
        MMA_Q(aA, 0, bA, 0); SCHEDB; VMW(8); BAR;   // completes A(0,1,NT-2)
        READ_AH(aB, 0, 1);                   LGKM(8); BAR; SCHEDB;
        MMA_Q(aA, 0, bB, 1); SCHEDB; VMW(6); BAR;   // completes A(1,0,NT-1)
        READ_AH(aA, 1, 0);                   LGKM(8); BAR; SCHEDB;
        MMA_Q(aB, 1, bB, 1); SCHEDB; VMW(4); BAR;   // completes B(1,0,NT-1)
        READ_BH(bB, 1, 0);                            BAR; SCHEDB;
        MMA_Q(aB, 1, bA, 0); SCHEDB; VMW(2); BAR;   // completes B(1,1,NT-1)
        // odd tile (buf1, NT-1)
        READ_BH(bA, 1, 1);                   LGKM(4); BAR; SCHEDB;
        MMA_Q(aA, 0, bB, 0); SCHEDB; VMW(0); BAR;   // completes A(1,1,NT-1)
        READ_AH(aB, 1, 1);                   LGKM(8); BAR; SCHEDB;
        MMA_Q(aA, 0, bA, 1); SCHEDB; BAR;
        LGKM(0); SCHEDB;
        MMA_Q(aB, 1, bA, 1); SCHEDB;
        MMA_Q(aB, 1, bB, 0);
    }

    // epilogue: same C/D mapping as verified baseline (rows quad*4+r, cols lm)
#pragma unroll
    for (int nf = 0; nf < 4; ++nf) {
        const int col = n0 + (wn << 6) + (nf << 4) + lm;
        const float bj = bias[col];
#pragma unroll
        for (int mf = 0; mf < 8; ++mf) {
            const int mb = m0 + (wm << 7) + (mf << 4) + (quad << 2);
#pragma unroll
            for (int r = 0; r < 4; ++r)
                C[(size_t)(mb + r) * N + col] = (OutT)(acc[mf][nf][r] + bj);
        }
    }
}

// ---------------------------------------------------------------- RMSNorm + 3D RoPE on q,k (in place, bf16)
__global__ void rmsrope(__bf16* __restrict__ qkv, const float* __restrict__ qw,
                        const float* __restrict__ kw) {
    int bn = blockIdx.x;            // b*2048 + n
    int n = bn & 2047;
    int tid = threadIdx.x, wave = tid >> 6, lane = tid & 63;
    int d0 = lane * 2;
    int t = n >> 8, hp = (n >> 4) & 15, wp = n & 15;
    float pos, fi;
    if (d0 < 44)      { pos = (float)t;  fi = (float)(d0 >> 1) * (2.0f / 44.0f); }
    else if (d0 < 86) { pos = (float)hp; fi = (float)((d0 - 44) >> 1) * (2.0f / 42.0f); }
    else              { pos = (float)wp; fi = (float)((d0 - 86) >> 1) * (2.0f / 42.0f); }
    float freq = expf(-fi * 9.210340371976184f);  // 10000^-fi
    float ang = pos * freq, sn, cs;
    sincosf(ang, &sn, &cs);
    float w0q = qw[d0], w1q = qw[d0 + 1], w0k = kw[d0], w1k = kw[d0 + 1];

    for (int h = wave; h < 24; h += 4) {
        size_t base = (size_t)bn * 9216 + h * 128 + d0;
        {
            bf16x2 xv = *(bf16x2*)(qkv + base);
            float x0 = (float)xv.x, x1 = (float)xv.y;
            float ss = x0 * x0 + x1 * x1;
            for (int m = 1; m < 64; m <<= 1) ss += __shfl_xor(ss, m, 64);
            float rr = rsqrtf(ss * (1.0f / 128.0f) + 1e-6f);
            float y0 = x0 * rr * w0q, y1 = x1 * rr * w1q;
            bf16x2 st; st.x = (__bf16)(y0 * cs - y1 * sn); st.y = (__bf16)(y1 * cs + y0 * sn);
            *(bf16x2*)(qkv + base) = st;
        }
        {
            bf16x2 xv = *(bf16x2*)(qkv + base + 3072);
            float x0 = (float)xv.x, x1 = (float)xv.y;
            float ss = x0 * x0 + x1 * x1;
            for (int m = 1; m < 64; m <<= 1) ss += __shfl_xor(ss, m, 64);
            float rr = rsqrtf(ss * (1.0f / 128.0f) + 1e-6f);
            float y0 = x0 * rr * w0k, y1 = x1 * rr * w1k;
            bf16x2 st; st.x = (__bf16)(y0 * cs - y1 * sn); st.y = (__bf16)(y1 * cs + y0 * sn);
            *(bf16x2*)(qkv + base + 3072) = st;
        }
    }
}

// ---------------------------------------------------------------- flash attention (S^T orientation)
// qkv: [4096][9216] bf16 (q/k normed+roped in place; v at 6144+h*128). O: [B][N][C] bf16.
// S^T = K·Q^T: lane holds qrow = lane&15, keys = quad*4+reg (+16j) -> per-lane softmax stats.
__global__ __launch_bounds__(256, 2)
void flash(const __bf16* __restrict__ qkv, __bf16* __restrict__ Oo) {
    __shared__ __align__(16) __bf16 Ks[64 * 136];   // [key][d]
    __shared__ __align__(16) __bf16 VTs[128 * 72];  // [d][key]
    __shared__ __align__(16) __bf16 Ps[128 * 72];   // [q row][key]
    int bh = blockIdx.x >> 4, qt = blockIdx.x & 15;
    int b = bh / 24, h = bh % 24;
    int q0 = qt * 128;
    int tid = threadIdx.x, wave = tid >> 6, lane = tid & 63;
    int lm = lane & 15, q8 = (lane >> 4) * 8, quad = lane >> 4;
    int wb = wave * 32;
    const float sc = 0.08838834764831845f;  // 1/sqrt(128)

    // Q fragments: rows wb+i*16+lm of this q-tile (used as MFMA B operand)
    bf16x8 qf[2][4];
    for (int i = 0; i < 2; ++i)
        for (int kk = 0; kk < 4; ++kk)
            qf[i][kk] = *(const bf16x8*)(qkv + (size_t)(b * 2048 + q0 + wb + i * 16 + lm) * 9216
                                         + h * 128 + kk * 32 + q8);

    float mrow[2] = {-__builtin_inff(), -__builtin_inff()};
    float lrow[2] = {0.f, 0.f};
    f32x4 oacc[2][8] = {};   // oacc[i][ct]: d = ct*16+quad*4+reg, qrow = wb+i*16+lm

    for (int nt = 0; nt < 32; ++nt) {
        int n0 = nt * 64;
        __syncthreads();
        for (int r = 0; r < 4; ++r) {
            int c = r * 256 + tid;                  // 0..1023
            int krow = c >> 4, kch = (c & 15) * 8;  // K: 64 x 16 chunks
            *(uint4*)(Ks + krow * 136 + kch) =
                *(const uint4*)(qkv + (size_t)(b * 2048 + n0 + krow) * 9216 + 3072 + h * 128 + kch);
            int vkey = c & 63, vch = (c >> 6) * 8;  // V: transpose on stage
            bf16x8 vv = *(const bf16x8*)(qkv + (size_t)(b * 2048 + n0 + vkey) * 9216 + 6144 + h * 128 + vch);
            for (int j = 0; j < 8; ++j)
                VTs[(vch + j) * 72 + vkey] = vv[j];
        }
        __syncthreads();

        // S^T = K Q^T : s[i][j] holds keys j*16+quad*4+reg for qrow wb+i*16+lm
        f32x4 s[2][4] = {};
        for (int kk = 0; kk < 4; ++kk) {
            bf16x8 bk[4];
            for (int j = 0; j < 4; ++j)
                bk[j] = *(const bf16x8*)(Ks + (j * 16 + lm) * 136 + kk * 32 + q8);
            for (int i = 0; i < 2; ++i)
                for (int j = 0; j < 4; ++j)
                    s[i][j] = MFMA16(bk[j], qf[i][kk], s[i][j]);
        }
        // online softmax: all 16 key-values for a row are in-lane; cross-quad = 2 shuffles
        for (int i = 0; i < 2; ++i) {
            float mx = -__builtin_inff();
            for (int j = 0; j < 4; ++j)
                for (int r = 0; r < 4; ++r)
                    mx = fmaxf(mx, s[i][j][r]);
            mx *= sc;
            mx = fmaxf(mx, __shfl_xor(mx, 16, 64));
            mx = fmaxf(mx, __shfl_xor(mx, 32, 64));
            float mn = fmaxf(mrow[i], mx);
            float alpha = __expf(mrow[i] - mn);
            mrow[i] = mn;
            float rs = 0.f;
            for (int j = 0; j < 4; ++j) {
                bf16x4 pw;
                for (int r = 0; r < 4; ++r) {
                    float p = __expf(s[i][j][r] * sc - mn);
                    rs += p;
                    pw[r] = (__bf16)p;
                }
                *(bf16x4*)(Ps + (wb + i * 16 + lm) * 72 + j * 16 + quad * 4) = pw;
            }
            rs += __shfl_xor(rs, 16, 64);
            rs += __shfl_xor(rs, 32, 64);
            lrow[i] = lrow[i] * alpha + rs;
            if (__any(alpha != 1.0f))
                for (int ct = 0; ct < 8; ++ct) oacc[i][ct] *= alpha;
        }
        // O^T += V^T P^T (P rows wb..wb+31 are wave-private)
        for (int kk = 0; kk < 2; ++kk) {
            bf16x8 ap[2];
            for (int i = 0; i < 2; ++i)
                ap[i] = *(const bf16x8*)(Ps + (wb + i * 16 + lm) * 72 + kk * 32 + q8);
            for (int ct = 0; ct < 8; ++ct) {
                bf16x8 bv = *(const bf16x8*)(VTs + (ct * 16 + lm) * 72 + kk * 32 + q8);
                for (int i = 0; i < 2; ++i)
                    oacc[i][ct] = MFMA16(bv, ap[i], oacc[i][ct]);
            }
        }
    }
    // epilogue: O /= l; lane owns qrow = wb+i*16+lm, d = ct*16+quad*4+[0..3]
    for (int i = 0; i < 2; ++i) {
        float inv = 1.0f / lrow[i];
        int row = q0 + wb + i * 16 + lm;
        size_t base = ((size_t)b * 2048 + row) * 3072 + h * 128 + quad * 4;
        for (int ct = 0; ct < 8; ++ct) {
            bf16x4 ov;
            for (int r = 0; r < 4; ++r) ov[r] = (__bf16)(oacc[i][ct][r] * inv);
            *(bf16x4*)(Oo + base + ct * 16) = ov;
        }
    }
}

// ---------------------------------------------------------------- launch
extern "C" void kernel_launch(void* const* d_in, const int* in_sizes, int n_in,
                              void* d_out, int out_size, void* d_ws, size_t ws_size,
                              hipStream_t stream) {
    const float* x      = (const float*)d_in[0];
    const float* qkv_w  = (const float*)d_in[1];
    const float* qkv_b  = (const float*)d_in[2];
    const float* qnw    = (const float*)d_in[3];
    const float* knw    = (const float*)d_in[4];
    const float* proj_w = (const float*)d_in[5];
    const float* proj_b = (const float*)d_in[6];
    float* out = (float*)d_out;
    char* ws = (char*)d_ws;

    // ws layout (bytes), total 176,160,768
    __bf16* xb   = (__bf16*)(ws + 0);           //  25,165,824  x bf16 (dead after gemm1)
    __bf16* attn = (__bf16*)(ws + 0);           //  alias: flash output [4096][3072] bf16
    __bf16* w1b  = (__bf16*)(ws + 25165824);    //  56,623,104  qkv_w bf16
    __bf16* w2b  = (__bf16*)(ws + 81788928);    //  18,874,368  proj_w bf16
    __bf16* qkvb = (__bf16*)(ws + 100663296);   //  75,497,472  qkv bf16 [4096][9216]

    pack_bf16<<<12288, 256, 0, stream>>>(x, xb, 3145728);
    pack_bf16<<<27648, 256, 0, stream>>>(qkv_w, w1b, 7077888);
    pack_bf16<<<9216, 256, 0, stream>>>(proj_w, w2b, 2359296);

    // QKV: [4096,3072] x [9216,3072]^T -> grid 16*36 = 576 blocks (%8==0)
    gemm256_bt_bias<__bf16><<<576, 512, 0, stream>>>(xb, w1b, qkv_b, qkvb, 4096, 9216, 3072);

    rmsrope<<<4096, 256, 0, stream>>>(qkvb, qnw, knw);

    flash<<<768, 256, 0, stream>>>(qkvb, attn);

    // proj: [4096,3072] x [3072,3072]^T -> grid 16*12 = 192 blocks (%8==0)
    gemm256_bt_bias<float><<<192, 512, 0, stream>>>(attn, w2b, proj_b, out, 4096, 3072, 3072);
}